// Round 1
// baseline (92.064 us; speedup 1.0000x reference)
//
#include <hip/hip_runtime.h>
#include <hip/hip_bf16.h>

#define IN_DIM 512
#define OUT_DIM 512
#define BATCH 4096
#define NC 9                  // 8 active spline basis slots + 1 silu slot
#define KDIM (IN_DIM * NC)    // 4608
#define NCTRL 17
#define TILE 128
#define BKT 64

typedef unsigned short ushort_t;
typedef __attribute__((ext_vector_type(8))) short short8;
typedef __attribute__((ext_vector_type(4))) float f32x4;

__device__ inline ushort_t to_bf16(float f) {
    union { float f; unsigned int i; } v; v.f = f;
    unsigned int r = v.i + 0x7FFF + ((v.i >> 16) & 1);   // round-to-nearest-even
    return (ushort_t)(r >> 16);
}

__device__ inline void gld16(const ushort_t* g, ushort_t* l) {
    __builtin_amdgcn_global_load_lds(
        (const __attribute__((address_space(1))) void*)g,
        (__attribute__((address_space(3))) void*)l, 16, 0, 0);
}

// Build A' bf16 [OUT_DIM][KDIM]: A'[o][i*9+c] = w_s[i,o]*ctrl[i,o,c] (c<8), w_b[i,o] (c==8)
__global__ void prep_A(const float* __restrict__ w_b, const float* __restrict__ w_s,
                       const float* __restrict__ ctrl, ushort_t* __restrict__ A) {
    int tid = blockIdx.x * 256 + threadIdx.x;
    int i = tid & (IN_DIM - 1);
    int o = tid >> 9;
    float ws = w_s[i * OUT_DIM + o];
    float wb = w_b[i * OUT_DIM + o];
    const float* cp = ctrl + (size_t)(i * OUT_DIM + o) * NCTRL;
    size_t base = (size_t)o * KDIM + i * NC;
#pragma unroll
    for (int c = 0; c < 8; c++) A[base + c] = to_bf16(ws * cp[c]);
    A[base + 8] = to_bf16(wb);
}

// Build B' bf16 [BATCH][KDIM]: B'[b][i*9+c] = basis_c(t) (c<8), silu(t) (c==8)
__global__ void prep_B(const float* __restrict__ x, const float* __restrict__ g,
                       const float* __restrict__ bound_p, ushort_t* __restrict__ Bt) {
    int tid = blockIdx.x * 256 + threadIdx.x;
    int i = tid & (IN_DIM - 1);
    int b = tid >> 9;
    float bound = bound_p[0];
    float t = x[(size_t)b * IN_DIM + i];
    t = fminf(fmaxf(t, -bound), bound);
    float u = (t + 8.0f) * 0.625f;       // knot spacing 1.6 -> 1/1.6 = 0.625 exact
    int j = (int)u;                       // interval: g[j] <= t < g[j+1], j in [2,7]
    j = min(max(j, 2), 7);
    // knots g[j-2 .. j+3]
    float gj[6];
#pragma unroll
    for (int r = 0; r < 6; r++) gj[r] = g[j - 2 + r];
    // de Boor: after p=3, Nv[r] = B_{j-3+r}^3(t)
    float Nv[4]; Nv[0] = 1.0f;
    float lv[4], rv[4];
#pragma unroll
    for (int p = 1; p <= 3; p++) {
        lv[p] = t - gj[3 - p];           // t - g[j+1-p]
        rv[p] = gj[2 + p] - t;           // g[j+p] - t
        float saved = 0.0f;
#pragma unroll
        for (int r = 0; r < p; r++) {
            float temp = Nv[r] / (rv[r + 1] + lv[p - r]);
            Nv[r] = saved + rv[r + 1] * temp;
            saved = lv[p - r] * temp;
        }
        Nv[p] = saved;
    }
    int c0 = j - 3;                       // may be -1 at j==2: drop Nv[0] (B_{-1} doesn't exist)
    size_t base = (size_t)b * KDIM + i * NC;
#pragma unroll
    for (int c = 0; c < 8; c++) {
        float v = 0.0f;
        v = (c == c0    ) ? Nv[0] : v;
        v = (c == c0 + 1) ? Nv[1] : v;
        v = (c == c0 + 2) ? Nv[2] : v;
        v = (c == c0 + 3) ? Nv[3] : v;
        Bt[base + c] = to_bf16(v);
    }
    float sg = 1.0f / (1.0f + expf(-t));
    Bt[base + 8] = to_bf16(t * sg);
}

// C[b][o] = sum_k B'[b][k] * A'[o][k]; C rows = batch (X operand), cols = out (Y operand).
// 128x128 tile, BK=64, 4 waves (2x2 of 64x64), 16x16x32 bf16 MFMA, split-K=2 via atomicAdd.
__global__ __launch_bounds__(256) void gemm_kan(const ushort_t* __restrict__ A,
                                                const ushort_t* __restrict__ Bt,
                                                float* __restrict__ out) {
    __shared__ ushort_t Xs[TILE * BKT];   // batch-side tile [128][64]
    __shared__ ushort_t Ys[TILE * BKT];   // out-side tile  [128][64]
    int tid = threadIdx.x;
    int lane = tid & 63;
    int w = tid >> 6;
    int bid = blockIdx.x;
    int kz = bid >> 7;            // split-K half
    int t2 = bid & 127;
    int ot = t2 & 3;              // out tile  (512/128)
    int bt = t2 >> 2;             // batch tile (4096/128)
    int brow0 = bt * TILE;
    int ocol0 = ot * TILE;
    int k0 = kz * (KDIM / 2);     // 0 or 2304

    int wr = w >> 1, wc = w & 1;  // wave sub-tile (64x64) within 128x128

    f32x4 acc[4][4];
#pragma unroll
    for (int m = 0; m < 4; m++)
#pragma unroll
        for (int n = 0; n < 4; n++) acc[m][n] = (f32x4){0.f, 0.f, 0.f, 0.f};

    int lr = lane >> 3;           // staging: lane's row within 8-row group
    int lcb = (lane & 7) * 8;     // staging: lane's bf16 col (16B granules)

    const int KSTEPS = (KDIM / 2) / BKT;   // 36
    for (int ks = 0; ks < KSTEPS; ks++) {
        int kcur = k0 + ks * BKT;
#pragma unroll
        for (int it = 0; it < 4; it++) {
            int row = it * 32 + w * 8;    // wave-uniform LDS dest
            gld16(Bt + (size_t)(brow0 + row + lr) * KDIM + kcur + lcb, &Xs[row * BKT]);
            gld16(A  + (size_t)(ocol0 + row + lr) * KDIM + kcur + lcb, &Ys[row * BKT]);
        }
        __syncthreads();
#pragma unroll
        for (int kk = 0; kk < 2; kk++) {
            short8 xf[4], yf[4];
            int kof = kk * 32 + (lane >> 4) * 8;
#pragma unroll
            for (int m = 0; m < 4; m++)
                xf[m] = *(const short8*)&Xs[(wr * 64 + m * 16 + (lane & 15)) * BKT + kof];
#pragma unroll
            for (int n = 0; n < 4; n++)
                yf[n] = *(const short8*)&Ys[(wc * 64 + n * 16 + (lane & 15)) * BKT + kof];
#pragma unroll
            for (int m = 0; m < 4; m++)
#pragma unroll
                for (int n = 0; n < 4; n++)
                    acc[m][n] = __builtin_amdgcn_mfma_f32_16x16x32_bf16(xf[m], yf[n], acc[m][n], 0, 0, 0);
        }
        __syncthreads();
    }
    // epilogue: C row=b=(lane>>4)*4+reg (+16m+64wr), col=o=lane&15 (+16n+64wc)
    int rgrp = lane >> 4;
    int cidx = lane & 15;
#pragma unroll
    for (int m = 0; m < 4; m++) {
#pragma unroll
        for (int n = 0; n < 4; n++) {
            int o_idx = ocol0 + wc * 64 + n * 16 + cidx;
#pragma unroll
            for (int r = 0; r < 4; r++) {
                int b_idx = brow0 + wr * 64 + m * 16 + rgrp * 4 + r;
                atomicAdd(out + (size_t)b_idx * OUT_DIM + o_idx, acc[m][n][r]);
            }
        }
    }
}

extern "C" void kernel_launch(void* const* d_in, const int* in_sizes, int n_in,
                              void* d_out, int out_size, void* d_ws, size_t ws_size,
                              hipStream_t stream) {
    const float* x     = (const float*)d_in[0];
    const float* w_b   = (const float*)d_in[1];
    const float* w_s   = (const float*)d_in[2];
    const float* ctrl  = (const float*)d_in[3];
    const float* g     = (const float*)d_in[4];
    const float* bound = (const float*)d_in[5];
    float* out = (float*)d_out;

    ushort_t* Abuf = (ushort_t*)d_ws;                              // 512*4608*2 = 4.72 MB
    ushort_t* Bbuf = (ushort_t*)((char*)d_ws + (size_t)(8u << 20)); // at 8 MB; 4096*4608*2 = 37.75 MB

    hipMemsetAsync(d_out, 0, (size_t)BATCH * OUT_DIM * sizeof(float), stream);
    prep_A<<<IN_DIM * OUT_DIM / 256, 256, 0, stream>>>(w_b, w_s, ctrl, Abuf);
    prep_B<<<BATCH * IN_DIM / 256, 256, 0, stream>>>(x, g, bound, Bbuf);
    gemm_kan<<<256, 256, 0, stream>>>(Abuf, Bbuf, out);
}